// Round 2
// baseline (625.503 us; speedup 1.0000x reference)
//
#include <hip/hip_runtime.h>

#define Bn 4
#define Tn 512
#define Mn 16
#define Dn 128
#define Pn 128
#define Hn 4
#define En 32
#define SCHUNK 128
#define SCALE 0.08838834764831845f  // 1 / (2*sqrt(32))

typedef unsigned short u16;
typedef unsigned int u32;

__device__ __forceinline__ u16 f2b(float f) {  // fp32 -> bf16 rne
  u32 x; __builtin_memcpy(&x, &f, 4);
  x += 0x7fffu + ((x >> 16) & 1u);
  return (u16)(x >> 16);
}
__device__ __forceinline__ float lof(u32 u) {
  u32 x = u << 16; float f; __builtin_memcpy(&f, &x, 4); return f;
}
__device__ __forceinline__ float hif(u32 u) {
  u32 x = u & 0xffff0000u; float f; __builtin_memcpy(&f, &x, 4); return f;
}
__device__ __forceinline__ void unp8(uint4 u, float* o) {
  o[0] = lof(u.x); o[1] = hif(u.x); o[2] = lof(u.y); o[3] = hif(u.y);
  o[4] = lof(u.z); o[5] = hif(u.z); o[6] = lof(u.w); o[7] = hif(u.w);
}

// ---------------------------------------------------------------- lengths ---
// mask[b,t,m] = (t < len[b]); recover len[b] = #nonzero of mask[b,:,0].
// Element 0 is always true (len >= T/2), so the first 4 bytes identify the
// encoding: i32 -> 0x00000001, f32 -> 0x3F800000, bf16 -> 0x3F803F80,
// bytes -> 0x01010101.
__global__ void lengths_kernel(const void* __restrict__ mask, int* __restrict__ len_out) {
  const int b = blockIdx.x;
  __shared__ int cnt[256];
  const u32 w0 = ((const u32*)mask)[0];
  const int mode = (w0 == 1u) ? 0 : (w0 == 0x3F800000u) ? 1
                 : (w0 == 0x3F803F80u) ? 2 : 3;
  int c = 0;
  for (int t = threadIdx.x; t < Tn; t += 256) {
    const size_t idx = ((size_t)b * Tn + t) * Mn;
    int nz;
    if (mode == 0)      nz = (((const int*)mask)[idx] != 0);
    else if (mode == 1) nz = (((const u32*)mask)[idx] != 0u);
    else if (mode == 2) nz = (((const u16*)mask)[idx] != 0);
    else                nz = (((const unsigned char*)mask)[idx] != 0);
    c += nz;
  }
  cnt[threadIdx.x] = c;
  __syncthreads();
  for (int s = 128; s > 0; s >>= 1) {
    if (threadIdx.x < (unsigned)s) cnt[threadIdx.x] += cnt[threadIdx.x + s];
    __syncthreads();
  }
  if (threadIdx.x == 0) len_out[b] = cnt[0];
}

// Storage helper: F32=1 -> fp32 workspace, F32=0 -> bf16 workspace.
template <int F32>
__device__ __forceinline__ void stg(void* p, size_t i, float v) {
  if (F32) ((float*)p)[i] = v; else ((u16*)p)[i] = f2b(v);
}

// ------------------------------------------------------------- projection ---
// One block = (m, 8 consecutive global rows bt). Thread p owns output column p
// of all 5 projections. Weight rows streamed once per block (amortized over 8
// input rows). Emits Qh=[q|q_t] (64 wide), Kh=[k|k_t], Vh (32 wide) in
// (b,m,h,t,.) layout.
template <int F32>
__global__ __launch_bounds__(128) void proj_kernel(
    const float* __restrict__ inp, const float* __restrict__ pos,
    const float* __restrict__ Wq, const float* __restrict__ Bq,
    const float* __restrict__ Wk, const float* __restrict__ Bk,
    const float* __restrict__ Wv, const float* __restrict__ Bv,
    const float* __restrict__ Wqt, const float* __restrict__ Bqt,
    const float* __restrict__ Wkt, const float* __restrict__ Bkt,
    void* __restrict__ Qh, void* __restrict__ Kh, void* __restrict__ Vh) {
  const int p = threadIdx.x;          // output column 0..127
  const int m = blockIdx.x % Mn;
  const int g = blockIdx.x / Mn;
  const int bt0 = g * 8;

  __shared__ float xs[8][Dn];
  __shared__ float ps[8][Dn];
#pragma unroll
  for (int r = 0; r < 8; ++r) {
    xs[r][p] = inp[((size_t)(bt0 + r) * Mn + m) * Dn + p];
    ps[r][p] = pos[(size_t)(bt0 + r) * Dn + p];
  }
  __syncthreads();

  float aq[8] = {}, ak[8] = {}, av[8] = {}, aqt[8] = {}, akt[8] = {};
  const size_t wb = ((size_t)m * Pn + p) * Dn;
  const float4* wq4  = (const float4*)(Wq + wb);
  const float4* wk4  = (const float4*)(Wk + wb);
  const float4* wv4  = (const float4*)(Wv + wb);
  const float4* wqt4 = (const float4*)(Wqt + wb);
  const float4* wkt4 = (const float4*)(Wkt + wb);

  for (int c = 0; c < Dn / 4; ++c) {  // 32 chunks of 4 d-values
    const float4 fq = wq4[c], fk = wk4[c], fv = wv4[c];
    const float4 fqt = wqt4[c], fkt = wkt4[c];
#pragma unroll
    for (int r = 0; r < 8; ++r) {
      const float4 x = *(const float4*)&xs[r][c * 4];   // broadcast (no conflict)
      const float4 pp = *(const float4*)&ps[r][c * 4];
      aq[r]  = fmaf(fq.x, x.x, fmaf(fq.y, x.y, fmaf(fq.z, x.z, fmaf(fq.w, x.w, aq[r]))));
      ak[r]  = fmaf(fk.x, x.x, fmaf(fk.y, x.y, fmaf(fk.z, x.z, fmaf(fk.w, x.w, ak[r]))));
      av[r]  = fmaf(fv.x, x.x, fmaf(fv.y, x.y, fmaf(fv.z, x.z, fmaf(fv.w, x.w, av[r]))));
      aqt[r] = fmaf(fqt.x, pp.x, fmaf(fqt.y, pp.y, fmaf(fqt.z, pp.z, fmaf(fqt.w, pp.w, aqt[r]))));
      akt[r] = fmaf(fkt.x, pp.x, fmaf(fkt.y, pp.y, fmaf(fkt.z, pp.z, fmaf(fkt.w, pp.w, akt[r]))));
    }
  }

  const float bq = Bq[m * Pn + p],  bk = Bk[m * Pn + p], bv = Bv[m * Pn + p];
  const float bqt = Bqt[m * Pn + p], bkt = Bkt[m * Pn + p];
  const int h = p >> 5, e = p & 31;
  const int b = bt0 / Tn;
#pragma unroll
  for (int r = 0; r < 8; ++r) {
    const int t = (bt0 + r) % Tn;
    const size_t ob = (((size_t)b * Mn + m) * Hn + h) * Tn + t;
    stg<F32>(Qh, ob * 64 + e,      aq[r] + bq);
    stg<F32>(Qh, ob * 64 + 32 + e, aqt[r] + bqt);
    stg<F32>(Kh, ob * 64 + e,      ak[r] + bk);
    stg<F32>(Kh, ob * 64 + 32 + e, akt[r] + bkt);
    stg<F32>(Vh, ob * 32 + e,      av[r] + bv);
  }
}

// -------------------------------------------------------------- attention ---
// One block per (b,m,h); one thread per query row t. 128-key chunks staged in
// LDS as fp32 (K 32KB + V 16KB); online softmax; keys s < min(t+1, len).
template <int F32>
__global__ __launch_bounds__(512) void attn_kernel(
    const void* __restrict__ Qh, const void* __restrict__ Kh,
    const void* __restrict__ Vh, const int* __restrict__ lens,
    float* __restrict__ out) {
  const int h = blockIdx.x % Hn;
  const int m = (blockIdx.x / Hn) % Mn;
  const int b = blockIdx.x / (Hn * Mn);
  const int len = lens[b];
  const int t = threadIdx.x;          // 0..511

  __shared__ __align__(16) float Kc[SCHUNK][64];
  __shared__ __align__(16) float Vc[SCHUNK][32];

  const size_t base = (((size_t)b * Mn + m) * Hn + h) * Tn;

  float q[64];
  if (F32) {
    const float4* q4 = (const float4*)((const float*)Qh + (base + t) * 64);
#pragma unroll
    for (int c = 0; c < 16; ++c) *(float4*)&q[c * 4] = q4[c];
  } else {
    const uint4* q4 = (const uint4*)((const u16*)Qh + (base + t) * 64);
#pragma unroll
    for (int c = 0; c < 8; ++c) unp8(q4[c], &q[c * 8]);
  }

  float mrow = -1e30f, l = 0.f;
  float acc[32];
#pragma unroll
  for (int e = 0; e < 32; ++e) acc[e] = 0.f;

  for (int s0 = 0; s0 < len; s0 += SCHUNK) {
    if (F32) {
      const float4* srck = (const float4*)((const float*)Kh + (base + s0) * 64);
      float4* dstk = (float4*)&Kc[0][0];
      for (int i = threadIdx.x; i < SCHUNK * 64 / 4; i += 512) dstk[i] = srck[i];
      const float4* srcv = (const float4*)((const float*)Vh + (base + s0) * 32);
      float4* dstv = (float4*)&Vc[0][0];
      for (int i = threadIdx.x; i < SCHUNK * 32 / 4; i += 512) dstv[i] = srcv[i];
    } else {
      const uint4* srck = (const uint4*)((const u16*)Kh + (base + s0) * 64);
      for (int i = threadIdx.x; i < SCHUNK * 64 / 8; i += 512) {
        float tmp[8]; unp8(srck[i], tmp);
#pragma unroll
        for (int j = 0; j < 8; ++j) (&Kc[0][0])[i * 8 + j] = tmp[j];
      }
      const uint4* srcv = (const uint4*)((const u16*)Vh + (base + s0) * 32);
      for (int i = threadIdx.x; i < SCHUNK * 32 / 8; i += 512) {
        float tmp[8]; unp8(srcv[i], tmp);
#pragma unroll
        for (int j = 0; j < 8; ++j) (&Vc[0][0])[i * 8 + j] = tmp[j];
      }
    }
    __syncthreads();

    const int shi = min(min(t + 1, len) - s0, SCHUNK);
    for (int si = 0; si < shi; ++si) {
      const float4* k4 = (const float4*)&Kc[si][0];  // same addr all lanes: broadcast
      float sc = 0.f;
#pragma unroll
      for (int j = 0; j < 16; ++j) {
        const float4 u = k4[j];
        sc = fmaf(u.x, q[4 * j + 0], sc);
        sc = fmaf(u.y, q[4 * j + 1], sc);
        sc = fmaf(u.z, q[4 * j + 2], sc);
        sc = fmaf(u.w, q[4 * j + 3], sc);
      }
      sc *= SCALE;
      const float mnew = fmaxf(mrow, sc);
      const float pr = __expf(sc - mnew);
      if (mnew > mrow) {
        const float corr = __expf(mrow - mnew);
        l *= corr;
#pragma unroll
        for (int e = 0; e < 32; ++e) acc[e] *= corr;
        mrow = mnew;
      }
      l += pr;
      const float4* v4 = (const float4*)&Vc[si][0];
#pragma unroll
      for (int j = 0; j < 8; ++j) {
        const float4 u = v4[j];
        acc[4 * j + 0] = fmaf(pr, u.x, acc[4 * j + 0]);
        acc[4 * j + 1] = fmaf(pr, u.y, acc[4 * j + 1]);
        acc[4 * j + 2] = fmaf(pr, u.z, acc[4 * j + 2]);
        acc[4 * j + 3] = fmaf(pr, u.w, acc[4 * j + 3]);
      }
    }
    __syncthreads();
  }

  const float rinv = 1.0f / l;        // s=0 always valid (len >= 1) -> l >= ~1
  const size_t ob = (((size_t)b * Tn + t) * Mn + m) * Pn + h * En;
#pragma unroll
  for (int j = 0; j < 8; ++j) {
    float4 o;
    o.x = acc[4 * j + 0] * rinv; o.y = acc[4 * j + 1] * rinv;
    o.z = acc[4 * j + 2] * rinv; o.w = acc[4 * j + 3] * rinv;
    *(float4*)&out[ob + 4 * j] = o;
  }
}

// ------------------------------------------------------------------ launch ---
extern "C" void kernel_launch(void* const* d_in, const int* in_sizes, int n_in,
                              void* d_out, int out_size, void* d_ws, size_t ws_size,
                              hipStream_t stream) {
  const float* inp = (const float*)d_in[0];
  const float* pos = (const float*)d_in[1];
  const void* mask = d_in[2];
  const float* Wq  = (const float*)d_in[3];
  const float* Bq  = (const float*)d_in[4];
  const float* Wk  = (const float*)d_in[5];
  const float* Bk  = (const float*)d_in[6];
  const float* Wv  = (const float*)d_in[7];
  const float* Bv  = (const float*)d_in[8];
  const float* Wqt = (const float*)d_in[9];
  const float* Bqt = (const float*)d_in[10];
  const float* Wkt = (const float*)d_in[11];
  const float* Bkt = (const float*)d_in[12];
  float* out = (float*)d_out;

  const size_t nQ = (size_t)Bn * Mn * Hn * Tn * 64;   // 8.4M elems
  const size_t nK = nQ;
  const size_t nV = (size_t)Bn * Mn * Hn * Tn * 32;
  const bool f32ws = ws_size >= (nQ + nK + nV) * 4 + 64;  // ws_size constant -> graph-safe

  const int proj_grid = (Bn * Tn / 8) * Mn;
  if (f32ws) {
    float* Qh = (float*)d_ws;
    float* Kh = Qh + nQ;
    float* Vh = Kh + nK;
    int* lens = (int*)(Vh + nV);
    lengths_kernel<<<Bn, 256, 0, stream>>>(mask, lens);
    proj_kernel<1><<<proj_grid, 128, 0, stream>>>(
        inp, pos, Wq, Bq, Wk, Bk, Wv, Bv, Wqt, Bqt, Wkt, Bkt, Qh, Kh, Vh);
    attn_kernel<1><<<Bn * Mn * Hn, 512, 0, stream>>>(Qh, Kh, Vh, lens, out);
  } else {
    u16* Qh = (u16*)d_ws;
    u16* Kh = Qh + nQ;
    u16* Vh = Kh + nK;
    int* lens = (int*)(Vh + nV);
    lengths_kernel<<<Bn, 256, 0, stream>>>(mask, lens);
    proj_kernel<0><<<proj_grid, 128, 0, stream>>>(
        inp, pos, Wq, Bq, Wk, Bk, Wv, Bv, Wqt, Bqt, Wkt, Bkt, Qh, Kh, Vh);
    attn_kernel<0><<<Bn * Mn * Hn, 512, 0, stream>>>(Qh, Kh, Vh, lens, out);
  }
}

// Round 3
// 168.426 us; speedup vs baseline: 3.7138x; 3.7138x over previous
//
#include <hip/hip_runtime.h>

#define Bn 4
#define Tn 512
#define Mn 16
#define Dn 128
#define Pn 128
#define Hn 4
#define En 32
#define SCALE 0.08838834764831845f  // 1 / (2*sqrt(32))

typedef unsigned short u16;
typedef unsigned int u32;
typedef short s16;
typedef __attribute__((ext_vector_type(8))) s16 bf16x8;   // 8 bf16 = 4 VGPRs
typedef __attribute__((ext_vector_type(4))) float f32x4;  // MFMA C/D

__device__ __forceinline__ u16 f2b(float f) {  // fp32 -> bf16 rne
  u32 x; __builtin_memcpy(&x, &f, 4);
  x += 0x7fffu + ((x >> 16) & 1u);
  return (u16)(x >> 16);
}
__device__ __forceinline__ bf16x8 ld8(const u16* p) {  // 16B frag load (LDS or global)
  bf16x8 r; __builtin_memcpy(&r, p, 16); return r;
}
__device__ __forceinline__ f32x4 mfma16(bf16x8 a, bf16x8 b, f32x4 c) {
  return __builtin_amdgcn_mfma_f32_16x16x32_bf16(a, b, c, 0, 0, 0);
}

// ---------------------------------------------------------------- lengths ---
// mask[b,t,m] = (t < len[b]); len[b] = #nonzero of mask[b,:,0]. Encoding probed
// from first word (element 0 always true): i32 / f32 / bf16-pair / bytes.
__global__ void lengths_kernel(const void* __restrict__ mask, int* __restrict__ len_out) {
  const int b = blockIdx.x;
  __shared__ int cnt[256];
  const u32 w0 = ((const u32*)mask)[0];
  const int mode = (w0 == 1u) ? 0 : (w0 == 0x3F800000u) ? 1
                 : (w0 == 0x3F803F80u) ? 2 : 3;
  int c = 0;
  for (int t = threadIdx.x; t < Tn; t += 256) {
    const size_t idx = ((size_t)b * Tn + t) * Mn;
    int nz;
    if (mode == 0)      nz = (((const int*)mask)[idx] != 0);
    else if (mode == 1) nz = (((const u32*)mask)[idx] != 0u);
    else if (mode == 2) nz = (((const u16*)mask)[idx] != 0);
    else                nz = (((const unsigned char*)mask)[idx] != 0);
    c += nz;
  }
  cnt[threadIdx.x] = c;
  __syncthreads();
  for (int s = 128; s > 0; s >>= 1) {
    if (threadIdx.x < (unsigned)s) cnt[threadIdx.x] += cnt[threadIdx.x + s];
    __syncthreads();
  }
  if (threadIdx.x == 0) len_out[b] = cnt[0];
}

// --------------------------------------------------------- projection MFMA ---
// Block = (rowtile of 128 rows over B*T, m, tsel in {q,k,v,qt,kt}).
// Stage X (or pos) tile + W tile fp32->bf16 into LDS (stride 136: 2-way bank
// alias only), 4 waves x 256 MFMA, epilogue adds bias (+SCALE fold for q/qt)
// and scatters bf16 to the (b,m,h,t,.) workspace layout.
__global__ __launch_bounds__(256) void proj_mfma(
    const float* __restrict__ inp, const float* __restrict__ pos,
    const float* __restrict__ Wq, const float* __restrict__ Bq,
    const float* __restrict__ Wk, const float* __restrict__ Bk,
    const float* __restrict__ Wv, const float* __restrict__ Bv,
    const float* __restrict__ Wqt, const float* __restrict__ Bqt,
    const float* __restrict__ Wkt, const float* __restrict__ Bkt,
    u16* __restrict__ Qh, u16* __restrict__ Kh, u16* __restrict__ Vh) {
  const int tid = threadIdx.x;
  const int bid = blockIdx.x;
  const int tsel = bid % 5;
  const int m = (bid / 5) % Mn;
  const int rt0 = (bid / (5 * Mn)) * 128;

  const float* W; const float* Bb; int usepos, doscale;
  switch (tsel) {
    case 0:  W = Wq;  Bb = Bq;  usepos = 0; doscale = 1; break;
    case 1:  W = Wk;  Bb = Bk;  usepos = 0; doscale = 0; break;
    case 2:  W = Wv;  Bb = Bv;  usepos = 0; doscale = 0; break;
    case 3:  W = Wqt; Bb = Bqt; usepos = 1; doscale = 1; break;
    default: W = Wkt; Bb = Bkt; usepos = 1; doscale = 0; break;
  }
  const float* A = usepos ? pos : inp;

  __shared__ __align__(16) u16 Xs[128 * 136];
  __shared__ __align__(16) u16 Ws[128 * 136];

  for (int idx = tid; idx < 128 * 32; idx += 256) {
    const int row = idx >> 5, c4 = (idx & 31) * 4;
    const size_t src = usepos ? ((size_t)(rt0 + row) * Dn + c4)
                              : (((size_t)(rt0 + row) * Mn + m) * Dn + c4);
    const float4 x = *(const float4*)(A + src);
    ushort4 xh; xh.x = f2b(x.x); xh.y = f2b(x.y); xh.z = f2b(x.z); xh.w = f2b(x.w);
    *(ushort4*)&Xs[row * 136 + c4] = xh;
    const float4 w = *(const float4*)(W + ((size_t)m * Pn + row) * Dn + c4);
    ushort4 wh; wh.x = f2b(w.x); wh.y = f2b(w.y); wh.z = f2b(w.z); wh.w = f2b(w.w);
    *(ushort4*)&Ws[row * 136 + c4] = wh;
  }
  __syncthreads();

  const int wv = tid >> 6, lane = tid & 63;
  const int quad = lane >> 4, l16 = lane & 15;

  f32x4 acc[2][8];
#pragma unroll
  for (int qs = 0; qs < 2; ++qs)
#pragma unroll
    for (int n = 0; n < 8; ++n) acc[qs][n] = (f32x4){0.f, 0.f, 0.f, 0.f};

#pragma unroll
  for (int kc = 0; kc < 4; ++kc) {
    const int ko = kc * 32 + quad * 8;
    const bf16x8 a0 = ld8(&Xs[(wv * 32 + l16) * 136 + ko]);
    const bf16x8 a1 = ld8(&Xs[(wv * 32 + 16 + l16) * 136 + ko]);
#pragma unroll
    for (int n = 0; n < 8; ++n) {
      const bf16x8 bn = ld8(&Ws[(n * 16 + l16) * 136 + ko]);
      acc[0][n] = mfma16(a0, bn, acc[0][n]);
      acc[1][n] = mfma16(a1, bn, acc[1][n]);
    }
  }

  u16* dst = (tsel == 2) ? Vh : ((tsel == 0 || tsel == 3) ? Qh : Kh);
  const int coloff = (tsel >= 3) ? 32 : 0;
  const int ostride = (tsel == 2) ? 32 : 64;
#pragma unroll
  for (int n = 0; n < 8; ++n) {
    const int p = n * 16 + l16;
    const float bias = Bb[m * Pn + p];
    const int hh = p >> 5, e = p & 31;
#pragma unroll
    for (int qs = 0; qs < 2; ++qs)
#pragma unroll
      for (int reg = 0; reg < 4; ++reg) {
        const int r = rt0 + wv * 32 + qs * 16 + quad * 4 + reg;
        float v = acc[qs][n][reg] + bias;
        if (doscale) v *= SCALE;
        const int b = r >> 9, t = r & (Tn - 1);
        const size_t ob = (((size_t)b * Mn + m) * Hn + hh) * Tn + t;
        dst[ob * ostride + coloff + e] = f2b(v);
      }
  }
}

// --------------------------------------------------------- attention MFMA ---
// Block = (b,m,h, 128-query tile); 4 waves, each owns 32 q-rows. Per 128-key
// chunk: stage Khat (row-major, stride 72) + V transposed (Vt[e][s], stride
// 136); S via MFMA (C-layout col=lane&15,row=quad*4+reg); fp32 online softmax
// with shuffle row-reductions; P -> LDS (bf16) -> A-layout readback; PV MFMA.
__global__ __launch_bounds__(256) void attn_mfma(
    const u16* __restrict__ Qh, const u16* __restrict__ Kh,
    const u16* __restrict__ Vh, const int* __restrict__ lens,
    float* __restrict__ out) {
  const int bid = blockIdx.x;
  const int qt = bid & 3;
  const int h = (bid >> 2) & (Hn - 1);
  const int m = (bid >> 4) & (Mn - 1);
  const int b = bid >> 8;
  const int len = lens[b];
  const int qt0 = qt * 128;

  __shared__ __align__(16) u16 Ks[128 * 72];
  __shared__ __align__(16) u16 Vt[32 * 136];
  __shared__ __align__(16) u16 Ps[128 * 136];

  const int tid = threadIdx.x;
  const int wv = tid >> 6, lane = tid & 63;
  const int quad = lane >> 4, l16 = lane & 15;
  const size_t base = (((size_t)b * Mn + m) * Hn + h) * Tn;

  bf16x8 aq[2][2];  // Q-frags straight from global (once per block)
#pragma unroll
  for (int qs = 0; qs < 2; ++qs)
#pragma unroll
    for (int kc = 0; kc < 2; ++kc)
      aq[qs][kc] = ld8(Qh + (base + qt0 + wv * 32 + qs * 16 + l16) * 64 + kc * 32 + quad * 8);

  f32x4 O[2][2];
#pragma unroll
  for (int qs = 0; qs < 2; ++qs)
#pragma unroll
    for (int es = 0; es < 2; ++es) O[qs][es] = (f32x4){0.f, 0.f, 0.f, 0.f};
  float mr[2][4], lr[2][4];
#pragma unroll
  for (int qs = 0; qs < 2; ++qs)
#pragma unroll
    for (int reg = 0; reg < 4; ++reg) { mr[qs][reg] = -1e30f; lr[qs][reg] = 0.f; }

  const int s_hi = min(qt0 + 128, len);  // always >= 1 (len >= T/2)
  for (int s0 = 0; s0 < s_hi; s0 += 128) {
    // stage Khat chunk (rows always < T: valid memory; mask handles validity)
    for (int idx = tid; idx < 128 * 8; idx += 256) {
      const int row = idx >> 3, c8 = (idx & 7) * 8;
      const uint4 u = *(const uint4*)(Kh + (base + s0 + row) * 64 + c8);
      *(uint4*)&Ks[row * 72 + c8] = u;
    }
    // stage V transposed: Vt[e][s]
    for (int idx = tid; idx < 128 * 4; idx += 256) {
      const int row = idx >> 2, c8 = (idx & 3) * 8;
      const uint4 u = *(const uint4*)(Vh + (base + s0 + row) * 32 + c8);
      const u16* us = (const u16*)&u;
#pragma unroll
      for (int j = 0; j < 8; ++j) Vt[(c8 + j) * 136 + row] = us[j];
    }
    __syncthreads();

    // S = Qhat . Khat^T  (SCALE pre-folded into Qhat)
    f32x4 S[2][8];
#pragma unroll
    for (int qs = 0; qs < 2; ++qs)
#pragma unroll
      for (int st = 0; st < 8; ++st) S[qs][st] = (f32x4){0.f, 0.f, 0.f, 0.f};
#pragma unroll
    for (int kc = 0; kc < 2; ++kc) {
      const int ko = kc * 32 + quad * 8;
#pragma unroll
      for (int st = 0; st < 8; ++st) {
        const bf16x8 bk = ld8(&Ks[(st * 16 + l16) * 72 + ko]);
        S[0][st] = mfma16(aq[0][kc], bk, S[0][st]);
        S[1][st] = mfma16(aq[1][kc], bk, S[1][st]);
      }
    }

    // online softmax (fp32) + P write (bf16)
#pragma unroll
    for (int qs = 0; qs < 2; ++qs) {
#pragma unroll
      for (int reg = 0; reg < 4; ++reg) {
        const int q = qt0 + wv * 32 + qs * 16 + quad * 4 + reg;
        float cmax = -1e30f;
#pragma unroll
        for (int st = 0; st < 8; ++st) {
          const int s = s0 + st * 16 + l16;
          if ((s <= q) && (s < len)) cmax = fmaxf(cmax, S[qs][st][reg]);
        }
        cmax = fmaxf(cmax, __shfl_xor(cmax, 1));
        cmax = fmaxf(cmax, __shfl_xor(cmax, 2));
        cmax = fmaxf(cmax, __shfl_xor(cmax, 4));
        cmax = fmaxf(cmax, __shfl_xor(cmax, 8));
        const float mold = mr[qs][reg];
        const float mnew = fmaxf(mold, cmax);  // every row has >=1 valid key/chunk
        const float alpha = __expf(mold - mnew);
        float rsum = 0.f;
#pragma unroll
        for (int st = 0; st < 8; ++st) {
          const int s = s0 + st * 16 + l16;
          const float p = ((s <= q) && (s < len)) ? __expf(S[qs][st][reg] - mnew) : 0.f;
          rsum += p;
          Ps[(wv * 32 + qs * 16 + quad * 4 + reg) * 136 + st * 16 + l16] = f2b(p);
        }
        rsum += __shfl_xor(rsum, 1);
        rsum += __shfl_xor(rsum, 2);
        rsum += __shfl_xor(rsum, 4);
        rsum += __shfl_xor(rsum, 8);
        lr[qs][reg] = lr[qs][reg] * alpha + rsum;
        mr[qs][reg] = mnew;
#pragma unroll
        for (int es = 0; es < 2; ++es) O[qs][es][reg] *= alpha;
      }
    }
    __syncthreads();

    // O += P . V   (P via A-layout readback, V via Vt rows)
#pragma unroll
    for (int kc = 0; kc < 4; ++kc) {
      const int ko = kc * 32 + quad * 8;
#pragma unroll
      for (int qs = 0; qs < 2; ++qs) {
        const bf16x8 ap = ld8(&Ps[(wv * 32 + qs * 16 + l16) * 136 + ko]);
#pragma unroll
        for (int es = 0; es < 2; ++es) {
          const bf16x8 bv = ld8(&Vt[(es * 16 + l16) * 136 + ko]);
          O[qs][es] = mfma16(ap, bv, O[qs][es]);
        }
      }
    }
    __syncthreads();
  }

  // epilogue: normalize, store fp32
#pragma unroll
  for (int qs = 0; qs < 2; ++qs)
#pragma unroll
    for (int reg = 0; reg < 4; ++reg) {
      const int t = qt0 + wv * 32 + qs * 16 + quad * 4 + reg;
      const float linv = 1.0f / lr[qs][reg];
#pragma unroll
      for (int es = 0; es < 2; ++es)
        out[(((size_t)b * Tn + t) * Mn + m) * Pn + h * En + es * 16 + l16] =
            O[qs][es][reg] * linv;
    }
}

// ------------------------------------------------------------------ launch ---
extern "C" void kernel_launch(void* const* d_in, const int* in_sizes, int n_in,
                              void* d_out, int out_size, void* d_ws, size_t ws_size,
                              hipStream_t stream) {
  const float* inp = (const float*)d_in[0];
  const float* pos = (const float*)d_in[1];
  const void* mask = d_in[2];
  const float* Wq  = (const float*)d_in[3];
  const float* Bq  = (const float*)d_in[4];
  const float* Wk  = (const float*)d_in[5];
  const float* Bk  = (const float*)d_in[6];
  const float* Wv  = (const float*)d_in[7];
  const float* Bv  = (const float*)d_in[8];
  const float* Wqt = (const float*)d_in[9];
  const float* Bqt = (const float*)d_in[10];
  const float* Wkt = (const float*)d_in[11];
  const float* Bkt = (const float*)d_in[12];
  float* out = (float*)d_out;

  const size_t nQ = (size_t)Bn * Mn * Hn * Tn * 64;   // 8.39M elems
  const size_t nV = (size_t)Bn * Mn * Hn * Tn * 32;
  u16* Qh = (u16*)d_ws;
  u16* Kh = Qh + nQ;
  u16* Vh = Kh + nQ;
  int* lens = (int*)(Vh + nV);

  lengths_kernel<<<Bn, 256, 0, stream>>>(mask, lens);
  proj_mfma<<<(Bn * Tn / 128) * Mn * 5, 256, 0, stream>>>(
      inp, pos, Wq, Bq, Wk, Bk, Wv, Bv, Wqt, Bqt, Wkt, Bkt, Qh, Kh, Vh);
  attn_mfma<<<Bn * Mn * Hn * (Tn / 128), 256, 0, stream>>>(Qh, Kh, Vh, lens, out);
}

// Round 4
// 151.267 us; speedup vs baseline: 4.1351x; 1.1134x over previous
//
#include <hip/hip_runtime.h>

#define Bn 4
#define Tn 512
#define Mn 16
#define Dn 128
#define Pn 128
#define Hn 4
#define SCALE 0.08838834764831845f  // 1 / (2*sqrt(32))

typedef unsigned short u16;
typedef unsigned int u32;
typedef short s16;
typedef __attribute__((ext_vector_type(8))) s16 bf16x8;   // 8 bf16 = 4 VGPRs
typedef __attribute__((ext_vector_type(4))) float f32x4;  // MFMA C/D

__device__ __forceinline__ u16 f2b(float f) {  // fp32 -> bf16 rne
  u32 x; __builtin_memcpy(&x, &f, 4);
  x += 0x7fffu + ((x >> 16) & 1u);
  return (u16)(x >> 16);
}
__device__ __forceinline__ u32 pack2(float a, float b) {
  return (u32)f2b(a) | ((u32)f2b(b) << 16);
}
__device__ __forceinline__ bf16x8 ld8(const u16* p) {  // 16B frag load
  bf16x8 r; __builtin_memcpy(&r, p, 16); return r;
}
__device__ __forceinline__ f32x4 mfma16(bf16x8 a, bf16x8 b, f32x4 c) {
  // D rows (quad*4+reg) <- a's m-index; D cols (lane&15) <- b's n-index
  return __builtin_amdgcn_mfma_f32_16x16x32_bf16(a, b, c, 0, 0, 0);
}

// ---------------------------------------------------------------- lengths ---
__global__ void lengths_kernel(const void* __restrict__ mask, int* __restrict__ len_out) {
  const int b = blockIdx.x;
  __shared__ int cnt[256];
  const u32 w0 = ((const u32*)mask)[0];
  const int mode = (w0 == 1u) ? 0 : (w0 == 0x3F800000u) ? 1
                 : (w0 == 0x3F803F80u) ? 2 : 3;
  int c = 0;
  for (int t = threadIdx.x; t < Tn; t += 256) {
    const size_t idx = ((size_t)b * Tn + t) * Mn;
    int nz;
    if (mode == 0)      nz = (((const int*)mask)[idx] != 0);
    else if (mode == 1) nz = (((const u32*)mask)[idx] != 0u);
    else if (mode == 2) nz = (((const u16*)mask)[idx] != 0);
    else                nz = (((const unsigned char*)mask)[idx] != 0);
    c += nz;
  }
  cnt[threadIdx.x] = c;
  __syncthreads();
  for (int s = 128; s > 0; s >>= 1) {
    if (threadIdx.x < (unsigned)s) cnt[threadIdx.x] += cnt[threadIdx.x + s];
    __syncthreads();
  }
  if (threadIdx.x == 0) len_out[b] = cnt[0];
}

// --------------------------------------------------------- projection MFMA ---
// Block = (rowtile 128, m, tsel). K-split staging (two 64-d halves) keeps LDS
// at 36.9KB -> 4 blocks/CU. Outputs: Qa/Ka/Qb/Kb as [bmh][t][32] bf16 (SCALE
// folded into Qa/Qb), V transposed as Vt [bmh][e][t] via packed 8B stores.
__global__ __launch_bounds__(256) void proj_mfma(
    const float* __restrict__ inp, const float* __restrict__ pos,
    const float* __restrict__ Wq, const float* __restrict__ Bq,
    const float* __restrict__ Wk, const float* __restrict__ Bk,
    const float* __restrict__ Wv, const float* __restrict__ Bv,
    const float* __restrict__ Wqt, const float* __restrict__ Bqt,
    const float* __restrict__ Wkt, const float* __restrict__ Bkt,
    u16* __restrict__ Qa, u16* __restrict__ Ka, u16* __restrict__ Qb,
    u16* __restrict__ Kb, u16* __restrict__ Vt) {
  const int tid = threadIdx.x;
  const int bid = blockIdx.x;
  const int tsel = bid % 5;
  const int m = (bid / 5) % Mn;
  const int rt0 = (bid / (5 * Mn)) * 128;

  const float* W; const float* Bb; int usepos, doscale;
  u16* dst;
  switch (tsel) {
    case 0:  W = Wq;  Bb = Bq;  usepos = 0; doscale = 1; dst = Qa; break;
    case 1:  W = Wk;  Bb = Bk;  usepos = 0; doscale = 0; dst = Ka; break;
    case 2:  W = Wv;  Bb = Bv;  usepos = 0; doscale = 0; dst = Vt; break;
    case 3:  W = Wqt; Bb = Bqt; usepos = 1; doscale = 1; dst = Qb; break;
    default: W = Wkt; Bb = Bkt; usepos = 1; doscale = 0; dst = Kb; break;
  }
  const float* A = usepos ? pos : inp;

  __shared__ __align__(16) u16 Xs[128 * 72];   // 18.4KB (64-d half, pad 8)
  __shared__ __align__(16) u16 Ws2[128 * 72];  // 18.4KB

  const int wv = tid >> 6, lane = tid & 63;
  const int quad = lane >> 4, l16 = lane & 15;

  f32x4 acc[2][8];
#pragma unroll
  for (int qs = 0; qs < 2; ++qs)
#pragma unroll
    for (int n = 0; n < 8; ++n) acc[qs][n] = (f32x4){0.f, 0.f, 0.f, 0.f};

  for (int kh = 0; kh < 2; ++kh) {
    for (int idx = tid; idx < 128 * 16; idx += 256) {
      const int row = idx >> 4, c4 = (idx & 15) * 4, col = kh * 64 + c4;
      const size_t sx = usepos ? ((size_t)(rt0 + row) * Dn + col)
                               : (((size_t)(rt0 + row) * Mn + m) * Dn + col);
      const float4 x = *(const float4*)(A + sx);
      ushort4 xh; xh.x = f2b(x.x); xh.y = f2b(x.y); xh.z = f2b(x.z); xh.w = f2b(x.w);
      *(ushort4*)&Xs[row * 72 + c4] = xh;
      const float4 w = *(const float4*)(W + ((size_t)m * Pn + row) * Dn + col);
      ushort4 wh; wh.x = f2b(w.x); wh.y = f2b(w.y); wh.z = f2b(w.z); wh.w = f2b(w.w);
      *(ushort4*)&Ws2[row * 72 + c4] = wh;
    }
    __syncthreads();
#pragma unroll
    for (int kc = 0; kc < 2; ++kc) {
      const int ko = kc * 32 + quad * 8;
      const bf16x8 a0 = ld8(&Xs[(wv * 32 + l16) * 72 + ko]);
      const bf16x8 a1 = ld8(&Xs[(wv * 32 + 16 + l16) * 72 + ko]);
#pragma unroll
      for (int n = 0; n < 8; ++n) {
        const bf16x8 bn = ld8(&Ws2[(n * 16 + l16) * 72 + ko]);
        acc[0][n] = mfma16(a0, bn, acc[0][n]);
        acc[1][n] = mfma16(a1, bn, acc[1][n]);
      }
    }
    __syncthreads();
  }

  const int b = rt0 >> 9;            // rowtile never crosses a batch boundary
  const int tl0 = (rt0 & (Tn - 1)) + wv * 32;
#pragma unroll
  for (int n = 0; n < 8; ++n) {
    const int h = n >> 1, e = (n & 1) * 16 + l16;
    const float bias = Bb[m * Pn + n * 16 + l16];
    const int bmh = (b * Mn + m) * Hn + h;
    if (tsel != 2) {
#pragma unroll
      for (int qs = 0; qs < 2; ++qs)
#pragma unroll
        for (int reg = 0; reg < 4; ++reg) {
          const int t = tl0 + qs * 16 + quad * 4 + reg;
          float v = acc[qs][n][reg] + bias;
          if (doscale) v *= SCALE;
          dst[((size_t)bmh * Tn + t) * 32 + e] = f2b(v);
        }
    } else {
      const size_t rowv = ((size_t)bmh * 32 + e) * Tn;
#pragma unroll
      for (int qs = 0; qs < 2; ++qs) {
        const int t0 = tl0 + qs * 16 + quad * 4;
        uint2 d;
        d.x = pack2(acc[qs][n][0] + bias, acc[qs][n][1] + bias);
        d.y = pack2(acc[qs][n][2] + bias, acc[qs][n][3] + bias);
        *(uint2*)&dst[rowv + t0] = d;
      }
    }
  }
}

// ------------------------------------------------------- attention (flash) ---
// Wave-autonomous: wave = 32 q-rows of one (b,m,h). S^T = Khat.Qhat^T so C
// cols = q (lane&15): softmax = in-lane + xor16/xor32 shuffles; P written as
// packed 8B runs to a PRIVATE per-wave LDS slab (no __syncthreads anywhere);
// O^T = V^T.P keeps q on l16. K/Q/V frags load straight from global (L2).
__global__ __launch_bounds__(256, 4) void attn_flash(
    const u16* __restrict__ Qa, const u16* __restrict__ Ka,
    const u16* __restrict__ Qb, const u16* __restrict__ Kb,
    const u16* __restrict__ Vt, const int* __restrict__ lens,
    float* __restrict__ out) {
  __shared__ __align__(16) u16 Ps[4 * 32 * 72];  // 18.4KB, per-wave slabs

  const int tid = threadIdx.x;
  const int wv = tid >> 6, lane = tid & 63;
  const int quad = lane >> 4, l16 = lane & 15;

  const int wu = blockIdx.x * 4 + wv;      // 0..4095
  const int qt = wu & 15;
  const int bmh = wu >> 4;
  const int b = bmh >> 6;                  // Mn*Hn = 64
  const int len = lens[b];
  const int q0 = qt * 32;

  const size_t rowbase = (size_t)bmh * Tn;
  const size_t vbase = (size_t)bmh * 32 * Tn;
  u16* myPs = &Ps[wv * 32 * 72];

  bf16x8 qf[2][2];
#pragma unroll
  for (int qs = 0; qs < 2; ++qs) {
    const size_t r = (rowbase + q0 + qs * 16 + l16) * 32 + quad * 8;
    qf[qs][0] = ld8(Qa + r);
    qf[qs][1] = ld8(Qb + r);
  }

  f32x4 O[2][2];  // [qs][es], D rows = e (quad*4+reg), cols = q (l16)
#pragma unroll
  for (int qs = 0; qs < 2; ++qs)
#pragma unroll
    for (int es = 0; es < 2; ++es) O[qs][es] = (f32x4){0.f, 0.f, 0.f, 0.f};
  float mrow[2] = {-1e30f, -1e30f}, lsum[2] = {0.f, 0.f};

  const int s_hi = min(q0 + 32, len);      // len >= T/2 >= 1
  for (int s0 = 0; s0 < s_hi; s0 += 64) {
    // S^T tiles: rows = keys (st*16 chunks), cols = q. Always 4 tiles
    // (loads stay in-bounds: s0+63 <= 511); masking handles validity.
    f32x4 S[2][4];
#pragma unroll
    for (int st = 0; st < 4; ++st) {
      const size_t kr = (rowbase + s0 + st * 16 + l16) * 32 + quad * 8;
      const bf16x8 k0 = ld8(Ka + kr);
      const bf16x8 k1 = ld8(Kb + kr);
#pragma unroll
      for (int qs = 0; qs < 2; ++qs)
        S[qs][st] = mfma16(k1, qf[qs][1], mfma16(k0, qf[qs][0],
                           st == -1 ? S[qs][st] : (f32x4){0.f, 0.f, 0.f, 0.f}));
    }

#pragma unroll
    for (int qs = 0; qs < 2; ++qs) {
      const int q = q0 + qs * 16 + l16;
      const int qcap = min(q, len - 1);    // valid <=> s <= qcap
      const int sb = s0 + quad * 4;
      float cmax = -1e30f;
#pragma unroll
      for (int st = 0; st < 4; ++st)
#pragma unroll
        for (int reg = 0; reg < 4; ++reg) {
          const int s = sb + st * 16 + reg;
          const float v = (s <= qcap) ? S[qs][st][reg] : -1e30f;
          S[qs][st][reg] = v;
          cmax = fmaxf(cmax, v);
        }
      cmax = fmaxf(cmax, __shfl_xor(cmax, 16));
      cmax = fmaxf(cmax, __shfl_xor(cmax, 32));
      const float mnew = fmaxf(mrow[qs], cmax);   // finite: every chunk has a valid key
      const float alpha = __expf(mrow[qs] - mnew);
      mrow[qs] = mnew;
      float rsum = 0.f;
      u32 pk[4][2];
#pragma unroll
      for (int st = 0; st < 4; ++st) {
        const float p0 = __expf(S[qs][st][0] - mnew);
        const float p1 = __expf(S[qs][st][1] - mnew);
        const float p2 = __expf(S[qs][st][2] - mnew);
        const float p3 = __expf(S[qs][st][3] - mnew);
        rsum += (p0 + p1) + (p2 + p3);
        pk[st][0] = pack2(p0, p1);
        pk[st][1] = pack2(p2, p3);
      }
      rsum += __shfl_xor(rsum, 16);
      rsum += __shfl_xor(rsum, 32);
      lsum[qs] = lsum[qs] * alpha + rsum;
#pragma unroll
      for (int es = 0; es < 2; ++es)
#pragma unroll
        for (int reg = 0; reg < 4; ++reg) O[qs][es][reg] *= alpha;
      // P -> private LDS slab (8B packed runs; same-wave ordering via lgkmcnt)
#pragma unroll
      for (int st = 0; st < 4; ++st) {
        uint2 d; d.x = pk[st][0]; d.y = pk[st][1];
        *(uint2*)&myPs[(qs * 16 + l16) * 72 + st * 16 + quad * 4] = d;
      }
    }

    // O^T += V^T . P
#pragma unroll
    for (int kc = 0; kc < 2; ++kc) {
      const int ko = kc * 32 + quad * 8;
      const bf16x8 pf0 = ld8(&myPs[l16 * 72 + ko]);
      const bf16x8 pf1 = ld8(&myPs[(16 + l16) * 72 + ko]);
      const bf16x8 vf0 = ld8(Vt + vbase + (size_t)l16 * Tn + s0 + ko);
      const bf16x8 vf1 = ld8(Vt + vbase + (size_t)(16 + l16) * Tn + s0 + ko);
      O[0][0] = mfma16(vf0, pf0, O[0][0]);
      O[0][1] = mfma16(vf1, pf0, O[0][1]);
      O[1][0] = mfma16(vf0, pf1, O[1][0]);
      O[1][1] = mfma16(vf1, pf1, O[1][1]);
    }
  }

  // epilogue: lane q = qs*16+l16 (matches state), e = es*16+quad*4+reg
  const int mm = (bmh >> 2) & (Mn - 1);
  const int h = bmh & (Hn - 1);
#pragma unroll
  for (int qs = 0; qs < 2; ++qs) {
    const float linv = 1.0f / lsum[qs];
    const int t = q0 + qs * 16 + l16;
    const size_t ob = (((size_t)b * Tn + t) * Mn + mm) * Pn + h * 32 + quad * 4;
#pragma unroll
    for (int es = 0; es < 2; ++es) {
      float4 o;
      o.x = O[qs][es][0] * linv; o.y = O[qs][es][1] * linv;
      o.z = O[qs][es][2] * linv; o.w = O[qs][es][3] * linv;
      *(float4*)&out[ob + es * 16] = o;
    }
  }
}

// ------------------------------------------------------------------ launch ---
extern "C" void kernel_launch(void* const* d_in, const int* in_sizes, int n_in,
                              void* d_out, int out_size, void* d_ws, size_t ws_size,
                              hipStream_t stream) {
  const float* inp = (const float*)d_in[0];
  const float* pos = (const float*)d_in[1];
  const void* mask = d_in[2];
  const float* Wq  = (const float*)d_in[3];
  const float* Bq  = (const float*)d_in[4];
  const float* Wk  = (const float*)d_in[5];
  const float* Bk  = (const float*)d_in[6];
  const float* Wv  = (const float*)d_in[7];
  const float* Bv  = (const float*)d_in[8];
  const float* Wqt = (const float*)d_in[9];
  const float* Bqt = (const float*)d_in[10];
  const float* Wkt = (const float*)d_in[11];
  const float* Bkt = (const float*)d_in[12];
  float* out = (float*)d_out;

  const size_t nA = (size_t)Bn * Mn * Hn * Tn * 32;  // 4.19M elems per array
  u16* Qa = (u16*)d_ws;
  u16* Ka = Qa + nA;
  u16* Qb = Ka + nA;
  u16* Kb = Qb + nA;
  u16* Vt = Kb + nA;
  int* lens = (int*)(Vt + nA);

  lengths_kernel<<<Bn, 256, 0, stream>>>(mask, lens);
  proj_mfma<<<(Bn * Tn / 128) * Mn * 5, 256, 0, stream>>>(
      inp, pos, Wq, Bq, Wk, Bk, Wv, Bv, Wqt, Bqt, Wkt, Bkt, Qa, Ka, Qb, Kb, Vt);
  attn_flash<<<Bn * Mn * Hn * (Tn / 32) / 4, 256, 0, stream>>>(
      Qa, Ka, Qb, Kb, Vt, lens, out);
}